// Round 3
// baseline (415.588 us; speedup 1.0000x reference)
//
#include <hip/hip_runtime.h>
#include <hip/hip_bf16.h>
#include <stdint.h>

// Problem constants (B=8192, D=256 fixed by reference setup_inputs)
#define NB 8192          // batch rows
#define ND 256           // feature dim (= full K)
#define NW 16384         // rows of W = [v; u]
#define BM 128           // rows per block
#define BN 64            // cols per tile
#define NSH 8            // half-strips
#define SHW 2048         // cols per half-strip
#define NTILES (SHW / BN)   // 32 tiles per block
// rows pre-scaled by rw*sqrt(1/T): every dot product == sim/T directly
#define SQRT_INVT 3.7796447f   // sqrt(1/0.07)

typedef __bf16 bf16x8 __attribute__((ext_vector_type(8)));
typedef float floatx4 __attribute__((ext_vector_type(4)));

__device__ __forceinline__ void gload_lds16(const void* g, void* l) {
    // async global->LDS, 16B per lane; LDS dest = wave-uniform base + lane*16
    __builtin_amdgcn_global_load_lds(
        (const __attribute__((address_space(1))) unsigned int*)g,
        (__attribute__((address_space(3))) unsigned int*)l,
        16, 0, 0);
}

// ---------------------------------------------------------------------------
// Kernel 1: W[row] = concat(v,u)[row] * (1/||row||) * sqrt(1/T), in bf16.
// One WAVE per row: float4 loads, shuffle reduce, ushort4 store.
// ---------------------------------------------------------------------------
__global__ __launch_bounds__(512) void prep_kernel(
    const float* __restrict__ u, const float* __restrict__ v,
    __hip_bfloat16* __restrict__ W)
{
    const int t    = threadIdx.x;
    const int row  = blockIdx.x * 8 + (t >> 6);       // 0..16383
    const int lane = t & 63;
    const float* src = (row < NB) ? (v + (size_t)row * ND)
                                  : (u + (size_t)(row - NB) * ND);
    float4 x = ((const float4*)src)[lane];
    float ss = x.x * x.x + x.y * x.y + x.z * x.z + x.w * x.w;
#pragma unroll
    for (int off = 1; off < 64; off <<= 1) ss += __shfl_xor(ss, off, 64);
    const float sc = rsqrtf(ss) * SQRT_INVT;          // norms ~16, eps clamp moot
    ushort4 o;
    __hip_bfloat16 h;
    h = __float2bfloat16(x.x * sc); o.x = *(const unsigned short*)&h;
    h = __float2bfloat16(x.y * sc); o.y = *(const unsigned short*)&h;
    h = __float2bfloat16(x.z * sc); o.z = *(const unsigned short*)&h;
    h = __float2bfloat16(x.w * sc); o.w = *(const unsigned short*)&h;
    ((ushort4*)(W + (size_t)row * ND))[lane] = o;
}

// ---------------------------------------------------------------------------
// Kernel 2: fused GEMM+exp+rowsum -- occupancy-first redesign.
// Round-2 post-mortem: 128KB LDS -> 1 block/CU -> 2 waves/SIMD; no pipe
// saturated (Mfma 40 / VALU 37 / LDS 29%) = latency-bound, and private
// per-wave staging doubled L2 traffic to 4 MB/CU. Fix both:
//  - A fragments load global->registers directly (no LDS, one-time, L2).
//  - B tiles (64 rows = 32 KB) staged block-shared (NO duplication, 2 MB/CU)
//    into a ring-2 of 32 KB slots: LDS = 64 KB -> 2 blocks/CU, 4 waves/SIMD.
//  - Grid 512 blocks (2/CU), each owns rows[rt*128,+128) x half-strip (2048).
//  - One __syncthreads per tile: drains only the 4 prefetch loads issued a
//    full compute-phase earlier; barrier convoy hidden by the second block.
//  - __launch_bounds__(512,4) pins VGPR<=128 (16 waves/CU cliff at 128).
// XCD map (b%8=XCD): per XCD 32 row-tiles (2MB A) + 2 half-strips (2MB B)
// = 4 MB = per-XCD L2.
// LDS swizzle unchanged: 16B chunk c of row r stored at c^(r&15).
// ---------------------------------------------------------------------------
__global__ __launch_bounds__(512, 4) void dcl_main(
    const __hip_bfloat16* __restrict__ W,   // 16384 x 256, pre-scaled
    float* __restrict__ partial,            // [8][8192] slot = half-strip
    float* __restrict__ pos)                // 8192
{
    const int b  = blockIdx.x;
    const int x  = b & 7;                   // XCD (dispatch round-robin)
    const int j  = b >> 3;
    const int sh = ((x & 3) << 1) | (j & 1);          // half-strip 0..7
    const int rt = (j >> 1) | ((x >> 2) << 5);        // row tile 0..63
    const int rb = rt * BM;

    const __hip_bfloat16* A = W + (size_t)NB * ND;    // u rows

    __shared__ __align__(16) char lds[65536];         // ring-2 x 32 KB

    const int tid  = threadIdx.x;
    const int wave = tid >> 6;
    const int lane = tid & 63;
    const int wm   = wave >> 2;             // 0..1 : 64-row group of A
    const int wn   = wave & 3;              // 0..3 : 16-col group of tile
    const int quad = lane >> 4;             // 0..3
    const int tcol = lane & 15;             // 0..15

#define STAGE(t, slot) do {                                                  \
    const int cbW_ = sh * SHW + (t) * BN;                                    \
    char* dst_ = lds + (slot) * 32768;                                       \
    _Pragma("unroll")                                                        \
    for (int i_ = 0; i_ < 4; i_++) {                                         \
        int o_ = i_ * 8192 + wave * 1024 + lane * 16;                        \
        int r_ = o_ >> 9;                        /* 512 B per row */         \
        int c_ = (o_ >> 4) & 31;                 /* 16B chunk */             \
        int cg_ = (c_ ^ (r_ & 15)) * 8;          /* swizzled k-offset */     \
        gload_lds16(W + (size_t)(cbW_ + r_) * ND + cg_,                      \
                    dst_ + i_ * 8192 + wave * 1024);                         \
    }                                                                        \
} while (0)

    // issue B tile0 first so its latency overlaps the af loads
    STAGE(0, 0);

    // ---- A fragments: global -> registers directly (64 VGPRs) ----
    // frag layout for 16x16x32: lane(quad,tcol) holds row tcol(+base),
    // k elems [ks*32 + quad*8, +8)  (natural W layout, no swizzle needed)
    bf16x8 af[4][8];
#pragma unroll
    for (int mt = 0; mt < 4; mt++) {
        const __hip_bfloat16* ar =
            A + (size_t)(rb + wm * 64 + mt * 16 + tcol) * ND + quad * 8;
#pragma unroll
        for (int ks = 0; ks < 8; ks++)
            af[mt][ks] = *(const bf16x8*)(ar + ks * 32);
    }

    // diag tile (wave-uniform): dp = global col of this wave's diag block
    const bool isuv = (sh < 4);
    int dp = rb + wm * 64 + (isuv ? 0 : NB);
    if ((dp >> 11) != sh) dp = 0x40000000;   // sentinel: never matches

    float rsum[4][4];
#pragma unroll
    for (int mt = 0; mt < 4; mt++)
#pragma unroll
        for (int rg = 0; rg < 4; rg++) rsum[mt][rg] = 0.f;

#pragma unroll 1
    for (int t = 0; t < NTILES; t++) {
        __syncthreads();   // tile t staged by all waves; slot (t+1)&1 free
        if (t + 1 < NTILES) STAGE(t + 1, (t + 1) & 1);
        __builtin_amdgcn_sched_barrier(0);

        const char* curB = lds + (t & 1) * 32768;
        floatx4 acc[4];
#pragma unroll
        for (int mt = 0; mt < 4; mt++) acc[mt] = (floatx4){0.f, 0.f, 0.f, 0.f};

        __builtin_amdgcn_s_setprio(1);
#pragma unroll
        for (int ks = 0; ks < 8; ks++) {
            // B row r = wn*16+tcol; r&15 == tcol -> chunk (ks*4+quad)^tcol
            bf16x8 bb = *(const bf16x8*)(curB + (wn * 16 + tcol) * 512 +
                                         ((((ks * 4) + quad) ^ tcol) << 4));
#pragma unroll
            for (int mt = 0; mt < 4; mt++)
                acc[mt] = __builtin_amdgcn_mfma_f32_16x16x32_bf16(
                    af[mt][ks], bb, acc[mt], 0, 0, 0);
        }
        __builtin_amdgcn_s_setprio(0);
        __builtin_amdgcn_sched_barrier(0);

        // Epilogue. C/D layout: col=lane&15, row=quad*4+reg (m89/m91).
        const int cb = sh * SHW + t * BN;
        if (cb != dp) {
#pragma unroll
            for (int mt = 0; mt < 4; mt++)
#pragma unroll
                for (int rg = 0; rg < 4; rg++)
                    rsum[mt][rg] += __expf(acc[mt][rg]);
        } else {
#pragma unroll
            for (int mt = 0; mt < 4; mt++)
#pragma unroll
                for (int rg = 0; rg < 4; rg++) {
                    int rl = mt * 16 + quad * 4 + rg;        // row in 64-blk
                    bool sel = (rl == wn * 16 + tcol);       // on diagonal
                    float sc = acc[mt][rg];
                    if (isuv && sel) pos[rb + wm * 64 + rl] = sc;
                    rsum[mt][rg] += sel ? 0.f : __expf(sc);
                }
        }
    }

#undef STAGE

    __syncthreads();   // all B reads done before LDS reuse for reduction

    // block-end reduction: quad-lane shuffle, then combine the 4 wn waves in LDS
#pragma unroll
    for (int mt = 0; mt < 4; mt++)
#pragma unroll
        for (int reg = 0; reg < 4; reg++) {
            float vsum = rsum[mt][reg];
            vsum += __shfl_xor(vsum, 1, 64);
            vsum += __shfl_xor(vsum, 2, 64);
            vsum += __shfl_xor(vsum, 4, 64);
            vsum += __shfl_xor(vsum, 8, 64);
            if (tcol == 0) {
                int lrow = wm * 64 + mt * 16 + quad * 4 + reg;
                ((float*)lds)[wn * 128 + lrow] = vsum;
            }
        }
    __syncthreads();
    if (tid < BM) {
        const float* lf = (const float*)lds;
        float t = lf[tid] + lf[128 + tid] + lf[256 + tid] + lf[384 + tid];
        partial[(size_t)sh * NB + rb + tid] = t;
    }
}

// ---------------------------------------------------------------------------
// Kernel 3: loss = mean_i( log(sum_half_strips partial[s][i]) - pos_i )
// ---------------------------------------------------------------------------
__global__ __launch_bounds__(1024) void finalize_kernel(
    const float* __restrict__ partial, const float* __restrict__ pos,
    float* __restrict__ out)
{
    const int t = threadIdx.x;
    float s = 0.f;
    for (int i = t; i < NB; i += 1024) {
        float tot = 0.f;
#pragma unroll
        for (int k = 0; k < NSH; k++) tot += partial[(size_t)k * NB + i];
        s += logf(tot) - pos[i];
    }
#pragma unroll
    for (int off = 32; off > 0; off >>= 1) s += __shfl_down(s, off, 64);
    __shared__ float wsum[16];
    if ((t & 63) == 0) wsum[t >> 6] = s;
    __syncthreads();
    if (t == 0) {
        float tot = 0.f;
#pragma unroll
        for (int i = 0; i < 16; i++) tot += wsum[i];
        out[0] = tot / (float)NB;
    }
}

extern "C" void kernel_launch(void* const* d_in, const int* in_sizes, int n_in,
                              void* d_out, int out_size, void* d_ws, size_t ws_size,
                              hipStream_t stream) {
    const float* u = (const float*)d_in[0];
    const float* v = (const float*)d_in[1];
    float* out = (float*)d_out;

    char* ws = (char*)d_ws;
    __hip_bfloat16* W = (__hip_bfloat16*)ws;                      // 8 MB
    float* partial = (float*)(ws + (size_t)NW * ND * sizeof(__hip_bfloat16));
    float* pos     = partial + NSH * NB;                          // 8192 floats

    prep_kernel<<<NW / 8, 512, 0, stream>>>(u, v, W);
    dcl_main<<<512, 512, 0, stream>>>(W, partial, pos);
    finalize_kernel<<<1, 1024, 0, stream>>>(partial, pos, out);
}

// Round 4
// 147.561 us; speedup vs baseline: 2.8164x; 2.8164x over previous
//
#include <hip/hip_runtime.h>
#include <hip/hip_bf16.h>
#include <stdint.h>

// Problem constants (B=8192, D=256 fixed by reference setup_inputs)
#define NB 8192          // batch rows
#define ND 256           // feature dim (= full K)
#define NW 16384         // rows of W = [v; u]
#define BM 128           // rows per block
#define BN 64            // cols per tile
#define NSH 8            // half-strips
#define SHW 2048         // cols per half-strip
#define NTILES (SHW / BN)   // 32 tiles per block
// rows pre-scaled by rw*sqrt(1/T): every dot product == sim/T directly
#define SQRT_INVT 3.7796447f   // sqrt(1/0.07)

typedef __bf16 bf16x8 __attribute__((ext_vector_type(8)));
typedef float floatx4 __attribute__((ext_vector_type(4)));

__device__ __forceinline__ void gload_lds16(const void* g, void* l) {
    // async global->LDS, 16B per lane; LDS dest = wave-uniform base + lane*16
    __builtin_amdgcn_global_load_lds(
        (const __attribute__((address_space(1))) unsigned int*)g,
        (__attribute__((address_space(3))) unsigned int*)l,
        16, 0, 0);
}

// ---------------------------------------------------------------------------
// Kernel 1: W[row] = concat(v,u)[row] * (1/||row||) * sqrt(1/T), in bf16.
// One WAVE per row: float4 loads, shuffle reduce, ushort4 store.
// ---------------------------------------------------------------------------
__global__ __launch_bounds__(512) void prep_kernel(
    const float* __restrict__ u, const float* __restrict__ v,
    __hip_bfloat16* __restrict__ W)
{
    const int t    = threadIdx.x;
    const int row  = blockIdx.x * 8 + (t >> 6);       // 0..16383
    const int lane = t & 63;
    const float* src = (row < NB) ? (v + (size_t)row * ND)
                                  : (u + (size_t)(row - NB) * ND);
    float4 x = ((const float4*)src)[lane];
    float ss = x.x * x.x + x.y * x.y + x.z * x.z + x.w * x.w;
#pragma unroll
    for (int off = 1; off < 64; off <<= 1) ss += __shfl_xor(ss, off, 64);
    const float sc = rsqrtf(ss) * SQRT_INVT;          // norms ~16, eps clamp moot
    ushort4 o;
    __hip_bfloat16 h;
    h = __float2bfloat16(x.x * sc); o.x = *(const unsigned short*)&h;
    h = __float2bfloat16(x.y * sc); o.y = *(const unsigned short*)&h;
    h = __float2bfloat16(x.z * sc); o.z = *(const unsigned short*)&h;
    h = __float2bfloat16(x.w * sc); o.w = *(const unsigned short*)&h;
    ((ushort4*)(W + (size_t)row * ND))[lane] = o;
}

// ---------------------------------------------------------------------------
// Kernel 2: fused GEMM+exp+rowsum -- occupancy redesign, spill-fixed.
// Round-3 post-mortem: __launch_bounds__(512,4) capped the unified reg file
// at 128 split 64 arch + 64 acc -> af[4][8] spilled to scratch (VGPR_Count
// 64, WRITE_SIZE 1.7->78 MB, FETCH 14 MB->1.19 GB = spill traffic, 347us).
// Fix: launch_bounds(512,2) (cap 256; live state ~90 regs -> no spill);
// 2 blocks/CU then comes from LDS=64KB + VGPR<=128, as round-3's occupancy
// counter (46%) already proved the structure delivers.
// Structure (kept from round 3):
//  - A fragments load global->registers directly (no LDS, one-time, L2).
//  - B tiles (64 rows = 32 KB) staged block-shared (2 MB/CU L2 traffic)
//    into a ring-2 of 32 KB slots: LDS = 64 KB.
//  - Grid 512 blocks (2/CU), each owns rows[rt*128,+128) x half-strip (2048).
//  - One __syncthreads per tile; drains prefetch issued a full compute
//    phase earlier; barrier convoy hidden by the co-resident second block.
// XCD map (b%8=XCD): per XCD 32 row-tiles (2MB A) + 2 half-strips (2MB B).
// LDS swizzle unchanged: 16B chunk c of row r stored at c^(r&15).
// ---------------------------------------------------------------------------
__global__ __launch_bounds__(512, 2) void dcl_main(
    const __hip_bfloat16* __restrict__ W,   // 16384 x 256, pre-scaled
    float* __restrict__ partial,            // [8][8192] slot = half-strip
    float* __restrict__ pos)                // 8192
{
    const int b  = blockIdx.x;
    const int x  = b & 7;                   // XCD (dispatch round-robin)
    const int j  = b >> 3;
    const int sh = ((x & 3) << 1) | (j & 1);          // half-strip 0..7
    const int rt = (j >> 1) | ((x >> 2) << 5);        // row tile 0..63
    const int rb = rt * BM;

    const __hip_bfloat16* A = W + (size_t)NB * ND;    // u rows

    __shared__ __align__(16) char lds[65536];         // ring-2 x 32 KB

    const int tid  = threadIdx.x;
    const int wave = tid >> 6;
    const int lane = tid & 63;
    const int wm   = wave >> 2;             // 0..1 : 64-row group of A
    const int wn   = wave & 3;              // 0..3 : 16-col group of tile
    const int quad = lane >> 4;             // 0..3
    const int tcol = lane & 15;             // 0..15

#define STAGE(t, slot) do {                                                  \
    const int cbW_ = sh * SHW + (t) * BN;                                    \
    char* dst_ = lds + (slot) * 32768;                                       \
    _Pragma("unroll")                                                        \
    for (int i_ = 0; i_ < 4; i_++) {                                         \
        int o_ = i_ * 8192 + wave * 1024 + lane * 16;                        \
        int r_ = o_ >> 9;                        /* 512 B per row */         \
        int c_ = (o_ >> 4) & 31;                 /* 16B chunk */             \
        int cg_ = (c_ ^ (r_ & 15)) * 8;          /* swizzled k-offset */     \
        gload_lds16(W + (size_t)(cbW_ + r_) * ND + cg_,                      \
                    dst_ + i_ * 8192 + wave * 1024);                         \
    }                                                                        \
} while (0)

    // issue B tile0 first so its latency overlaps the af loads
    STAGE(0, 0);

    // ---- A fragments: global -> registers directly (32 VGPRs) ----
    // frag layout for 16x16x32: lane(quad,tcol) holds row tcol(+base),
    // k elems [ks*32 + quad*8, +8)  (natural W layout, no swizzle needed)
    bf16x8 af[4][8];
#pragma unroll
    for (int mt = 0; mt < 4; mt++) {
        const __hip_bfloat16* ar =
            A + (size_t)(rb + wm * 64 + mt * 16 + tcol) * ND + quad * 8;
#pragma unroll
        for (int ks = 0; ks < 8; ks++)
            af[mt][ks] = *(const bf16x8*)(ar + ks * 32);
    }

    // diag tile (wave-uniform): dp = global col of this wave's diag block
    const bool isuv = (sh < 4);
    int dp = rb + wm * 64 + (isuv ? 0 : NB);
    if ((dp >> 11) != sh) dp = 0x40000000;   // sentinel: never matches

    float rsum[4][4];
#pragma unroll
    for (int mt = 0; mt < 4; mt++)
#pragma unroll
        for (int rg = 0; rg < 4; rg++) rsum[mt][rg] = 0.f;

#pragma unroll 1
    for (int t = 0; t < NTILES; t++) {
        __syncthreads();   // tile t staged by all waves; slot (t+1)&1 free
        if (t + 1 < NTILES) STAGE(t + 1, (t + 1) & 1);
        __builtin_amdgcn_sched_barrier(0);

        const char* curB = lds + (t & 1) * 32768;
        floatx4 acc[4];
#pragma unroll
        for (int mt = 0; mt < 4; mt++) acc[mt] = (floatx4){0.f, 0.f, 0.f, 0.f};

        __builtin_amdgcn_s_setprio(1);
#pragma unroll
        for (int ks = 0; ks < 8; ks++) {
            // B row r = wn*16+tcol; r&15 == tcol -> chunk (ks*4+quad)^tcol
            bf16x8 bb = *(const bf16x8*)(curB + (wn * 16 + tcol) * 512 +
                                         ((((ks * 4) + quad) ^ tcol) << 4));
#pragma unroll
            for (int mt = 0; mt < 4; mt++)
                acc[mt] = __builtin_amdgcn_mfma_f32_16x16x32_bf16(
                    af[mt][ks], bb, acc[mt], 0, 0, 0);
        }
        __builtin_amdgcn_s_setprio(0);
        __builtin_amdgcn_sched_barrier(0);

        // Epilogue. C/D layout: col=lane&15, row=quad*4+reg (m89/m91).
        const int cb = sh * SHW + t * BN;
        if (cb != dp) {
#pragma unroll
            for (int mt = 0; mt < 4; mt++)
#pragma unroll
                for (int rg = 0; rg < 4; rg++)
                    rsum[mt][rg] += __expf(acc[mt][rg]);
        } else {
#pragma unroll
            for (int mt = 0; mt < 4; mt++)
#pragma unroll
                for (int rg = 0; rg < 4; rg++) {
                    int rl = mt * 16 + quad * 4 + rg;        // row in 64-blk
                    bool sel = (rl == wn * 16 + tcol);       // on diagonal
                    float sc = acc[mt][rg];
                    if (isuv && sel) pos[rb + wm * 64 + rl] = sc;
                    rsum[mt][rg] += sel ? 0.f : __expf(sc);
                }
        }
    }

#undef STAGE

    __syncthreads();   // all B reads done before LDS reuse for reduction

    // block-end reduction: quad-lane shuffle, then combine the 4 wn waves in LDS
#pragma unroll
    for (int mt = 0; mt < 4; mt++)
#pragma unroll
        for (int reg = 0; reg < 4; reg++) {
            float vsum = rsum[mt][reg];
            vsum += __shfl_xor(vsum, 1, 64);
            vsum += __shfl_xor(vsum, 2, 64);
            vsum += __shfl_xor(vsum, 4, 64);
            vsum += __shfl_xor(vsum, 8, 64);
            if (tcol == 0) {
                int lrow = wm * 64 + mt * 16 + quad * 4 + reg;
                ((float*)lds)[wn * 128 + lrow] = vsum;
            }
        }
    __syncthreads();
    if (tid < BM) {
        const float* lf = (const float*)lds;
        float t = lf[tid] + lf[128 + tid] + lf[256 + tid] + lf[384 + tid];
        partial[(size_t)sh * NB + rb + tid] = t;
    }
}

// ---------------------------------------------------------------------------
// Kernel 3: loss = mean_i( log(sum_half_strips partial[s][i]) - pos_i )
// ---------------------------------------------------------------------------
__global__ __launch_bounds__(1024) void finalize_kernel(
    const float* __restrict__ partial, const float* __restrict__ pos,
    float* __restrict__ out)
{
    const int t = threadIdx.x;
    float s = 0.f;
    for (int i = t; i < NB; i += 1024) {
        float tot = 0.f;
#pragma unroll
        for (int k = 0; k < NSH; k++) tot += partial[(size_t)k * NB + i];
        s += logf(tot) - pos[i];
    }
#pragma unroll
    for (int off = 32; off > 0; off >>= 1) s += __shfl_down(s, off, 64);
    __shared__ float wsum[16];
    if ((t & 63) == 0) wsum[t >> 6] = s;
    __syncthreads();
    if (t == 0) {
        float tot = 0.f;
#pragma unroll
        for (int i = 0; i < 16; i++) tot += wsum[i];
        out[0] = tot / (float)NB;
    }
}

extern "C" void kernel_launch(void* const* d_in, const int* in_sizes, int n_in,
                              void* d_out, int out_size, void* d_ws, size_t ws_size,
                              hipStream_t stream) {
    const float* u = (const float*)d_in[0];
    const float* v = (const float*)d_in[1];
    float* out = (float*)d_out;

    char* ws = (char*)d_ws;
    __hip_bfloat16* W = (__hip_bfloat16*)ws;                      // 8 MB
    float* partial = (float*)(ws + (size_t)NW * ND * sizeof(__hip_bfloat16));
    float* pos     = partial + NSH * NB;                          // 8192 floats

    prep_kernel<<<NW / 8, 512, 0, stream>>>(u, v, W);
    dcl_main<<<512, 512, 0, stream>>>(W, partial, pos);
    finalize_kernel<<<1, 1024, 0, stream>>>(partial, pos, out);
}

// Round 5
// 144.675 us; speedup vs baseline: 2.8726x; 1.0200x over previous
//
#include <hip/hip_runtime.h>
#include <hip/hip_bf16.h>
#include <stdint.h>

// Problem constants (B=8192, D=256 fixed by reference setup_inputs)
#define NB 8192          // batch rows
#define ND 256           // feature dim (= full K)
#define NW 16384         // rows of W = [v; u]
#define BM 128           // rows per block
#define BN 64            // cols per tile (wave slice = 16 rows)
#define NSTRIP 4         // column strips
#define STRIPW 4096      // cols per strip
#define NTILES (STRIPW / BN)   // 64 tiles per block
#define NU (NTILES * 2)        // 128 half-K pipeline units
// rows pre-scaled by rw*sqrt(1/T): every dot product == sim/T directly
#define SQRT_INVT 3.7796447f   // sqrt(1/0.07)

typedef __bf16 bf16x8 __attribute__((ext_vector_type(8)));
typedef float floatx4 __attribute__((ext_vector_type(4)));

__device__ __forceinline__ void gload_lds16(const void* g, void* l) {
    // async global->LDS, 16B per lane; LDS dest = wave-uniform base + lane*16
    __builtin_amdgcn_global_load_lds(
        (const __attribute__((address_space(1))) unsigned int*)g,
        (__attribute__((address_space(3))) unsigned int*)l,
        16, 0, 0);
}

// ---------------------------------------------------------------------------
// Kernel 1: W[row] = concat(v,u)[row] * (1/||row||) * sqrt(1/T), in bf16.
// One WAVE per row. Also zeroes out[0] for finalize's atomicAdd.
// ---------------------------------------------------------------------------
__global__ __launch_bounds__(512) void prep_kernel(
    const float* __restrict__ u, const float* __restrict__ v,
    __hip_bfloat16* __restrict__ W, float* __restrict__ out)
{
    const int t    = threadIdx.x;
    if (blockIdx.x == 0 && t == 0) out[0] = 0.f;
    const int row  = blockIdx.x * 8 + (t >> 6);       // 0..16383
    const int lane = t & 63;
    const float* src = (row < NB) ? (v + (size_t)row * ND)
                                  : (u + (size_t)(row - NB) * ND);
    float4 x = ((const float4*)src)[lane];
    float ss = x.x * x.x + x.y * x.y + x.z * x.z + x.w * x.w;
#pragma unroll
    for (int off = 1; off < 64; off <<= 1) ss += __shfl_xor(ss, off, 64);
    const float sc = rsqrtf(ss) * SQRT_INVT;          // norms ~16, eps clamp moot
    ushort4 o;
    __hip_bfloat16 h;
    h = __float2bfloat16(x.x * sc); o.x = *(const unsigned short*)&h;
    h = __float2bfloat16(x.y * sc); o.y = *(const unsigned short*)&h;
    h = __float2bfloat16(x.z * sc); o.z = *(const unsigned short*)&h;
    h = __float2bfloat16(x.w * sc); o.w = *(const unsigned short*)&h;
    ((ushort4*)(W + (size_t)row * ND))[lane] = o;
}

// ---------------------------------------------------------------------------
// Kernel 2: fused GEMM+exp+rowsum -- barrier-free + counted-vmcnt pipeline.
// Round-4 post-mortem: 2-blocks/CU unreachable (total arch+acc VGPR > 128;
// forcing it spills, r3). So optimize WITHIN 2 waves/SIMD: r2's barrier-free
// private staging (71.5us, Mfma 40.5%) stalled on per-tile vmcnt(0) full
// drains vs L2-under-load latency. Fix = T4 counted waits + deeper ring:
//  - staging unit = half-K slice (16 rows x 128 k = 4 KB), ring-4 per wave
//    (16 KB/wave, 128 KB LDS), NO __syncthreads in main loop.
//  - steady state: 3 units (12 loads) in flight, s_waitcnt vmcnt(12);
//    tail peeled at vmcnt(8)/(4)/(0). Never a full drain mid-loop.
//  - A fragments global->reg (af[4][8], 32 VGPR), one-time from L2.
//  - sched_barrier(0) fences each {stage,wait}->{compute} boundary (rule 18).
// Swizzle: 16B chunk c of 256B half-row r stored at c^r (4-bit, bijective);
// read side applies same XOR -> 2 lanes/bank max (free, m136).
// XCD map (r2's): s=(b>>1)&3, rt=((b>>3)<<1)|(b&1); per-XCD B strip ~1MB L2.
// ---------------------------------------------------------------------------
__global__ __launch_bounds__(512, 2) void dcl_main(
    const __hip_bfloat16* __restrict__ W,   // 16384 x 256, pre-scaled
    float* __restrict__ partial,            // [4][8192] slot = strip
    float* __restrict__ pos)                // 8192
{
    const int b  = blockIdx.x;
    const int s  = (b >> 1) & 3;                    // strip; XCD(b)=b%8 in {2s,2s+1}
    const int rt = ((b >> 3) << 1) | (b & 1);       // row tile 0..63
    const int rb = rt * BM;

    const __hip_bfloat16* A = W + (size_t)NB * ND;  // u rows

    __shared__ __align__(16) char lds[131072];      // 8 waves x ring-4 x 4 KB

    const int tid  = threadIdx.x;
    const int wave = tid >> 6;
    const int lane = tid & 63;
    const int wm   = wave >> 2;             // 0..1 : 64-row group of A
    const int wn   = wave & 3;              // 0..3 : 16-col group of tile
    const int quad = lane >> 4;             // 0..3
    const int tcol = lane & 15;             // 0..15
    const int rh4  = lane >> 4;             // stage: row within 4-row group
    const int cc   = lane & 15;             // stage: 16B chunk index (0..15)

    char* const wbuf  = lds + wave * 16384; // private ring-4
    const int   sbase = s * STRIPW;

// unit u = (tile u>>1, half u&1). 16 rows x 128 k = 4 KB, 4 loads/wave.
#define STAGE(u) do {                                                        \
    const int tu_ = (u) >> 1, h_ = (u) & 1;                                  \
    const int rowb_ = sbase + tu_ * BN + wn * 16;                            \
    char* dst_ = wbuf + ((u) & 3) * 4096;                                    \
    _Pragma("unroll")                                                        \
    for (int i_ = 0; i_ < 4; i_++) {                                         \
        int r_ = i_ * 4 + rh4;                                               \
        gload_lds16(W + (size_t)(rowb_ + r_) * ND + h_ * 128                 \
                      + ((cc ^ r_) << 3),                                    \
                    dst_ + i_ * 1024);                                       \
    }                                                                        \
} while (0)

#define COMPUTE_HALF(u) do {                                                 \
    const char* sb_ = wbuf + ((u) & 3) * 4096;                               \
    const int h_ = (u) & 1;                                                  \
    __builtin_amdgcn_s_setprio(1);                                           \
    _Pragma("unroll")                                                        \
    for (int ks_ = 0; ks_ < 4; ks_++) {                                      \
        bf16x8 bb_ = *(const bf16x8*)(sb_ + tcol * 256 +                     \
                                      ((((ks_ * 4) + quad) ^ tcol) << 4));   \
        _Pragma("unroll")                                                    \
        for (int mt_ = 0; mt_ < 4; mt_++)                                    \
            acc[mt_] = __builtin_amdgcn_mfma_f32_16x16x32_bf16(              \
                af[mt_][h_ * 4 + ks_], bb_, acc[mt_], 0, 0, 0);              \
    }                                                                        \
    __builtin_amdgcn_s_setprio(0);                                           \
} while (0)

#define ACC_INIT() do {                                                      \
    _Pragma("unroll")                                                        \
    for (int mt_ = 0; mt_ < 4; mt_++) acc[mt_] = (floatx4){0.f,0.f,0.f,0.f}; \
} while (0)

#define WAITV(n) do {                                                        \
    asm volatile("s_waitcnt vmcnt(" #n ")" ::: "memory");                    \
    __builtin_amdgcn_sched_barrier(0);                                       \
} while (0)

// Epilogue for tile t. C/D layout: col=lane&15, row=quad*4+reg (m89/m91).
#define EPILOGUE(t) do {                                                     \
    const int cb_ = sbase + (t) * BN;                                        \
    if (cb_ != dp) {                                                         \
        _Pragma("unroll")                                                    \
        for (int mt_ = 0; mt_ < 4; mt_++)                                    \
            _Pragma("unroll")                                                \
            for (int rg_ = 0; rg_ < 4; rg_++)                                \
                rsum[mt_][rg_] += __expf(acc[mt_][rg_]);                     \
    } else {                                                                 \
        _Pragma("unroll")                                                    \
        for (int mt_ = 0; mt_ < 4; mt_++)                                    \
            _Pragma("unroll")                                                \
            for (int rg_ = 0; rg_ < 4; rg_++) {                              \
                int rl_ = mt_ * 16 + quad * 4 + rg_;                         \
                bool sel_ = (rl_ == wn * 16 + tcol);                         \
                float sc_ = acc[mt_][rg_];                                   \
                if (isuv && sel_) pos[rb + wm * 64 + rl_] = sc_;             \
                rsum[mt_][rg_] += sel_ ? 0.f : __expf(sc_);                  \
            }                                                                \
    }                                                                        \
} while (0)

    // prologue: 3 units in flight before first compute
    STAGE(0); STAGE(1); STAGE(2);

    // ---- A fragments: global -> registers directly (32 VGPRs) ----
    // 16x16x32 A-frag: lane(quad,tcol) = row tcol(+base), k [ks*32+quad*8,+8)
    bf16x8 af[4][8];
#pragma unroll
    for (int mt = 0; mt < 4; mt++) {
        const __hip_bfloat16* ar =
            A + (size_t)(rb + wm * 64 + mt * 16 + tcol) * ND + quad * 8;
#pragma unroll
        for (int ks = 0; ks < 8; ks++)
            af[mt][ks] = *(const bf16x8*)(ar + ks * 32);
    }

    // diag tile (wave-uniform): dp = global col of this wave's diag block
    const bool isuv = (s < 2);
    int dp = rb + wm * 64 + (isuv ? 0 : NB);
    if ((dp >> 12) != s) dp = 0x40000000;   // sentinel: never matches

    float rsum[4][4];
#pragma unroll
    for (int mt = 0; mt < 4; mt++)
#pragma unroll
        for (int rg = 0; rg < 4; rg++) rsum[mt][rg] = 0.f;

    floatx4 acc[4];

    // main loop: tiles 0..61 (units 0..123; stages reach unit 126)
#pragma unroll 1
    for (int t = 0; t < NTILES - 2; t++) {
        const int u0 = 2 * t;
        ACC_INIT();
        STAGE(u0 + 3);
        WAITV(12);                 // unit u0 resident (3 units remain in flight)
        COMPUTE_HALF(u0);
        STAGE(u0 + 4);
        WAITV(12);                 // unit u0+1 resident
        COMPUTE_HALF(u0 + 1);
        __builtin_amdgcn_sched_barrier(0);
        EPILOGUE(t);
    }
    // tile 62: units 124,125 (stage 127 at even; pipeline starts draining)
    {
        ACC_INIT();
        STAGE(127);
        WAITV(12); COMPUTE_HALF(124);
        WAITV(8);  COMPUTE_HALF(125);
        __builtin_amdgcn_sched_barrier(0);
        EPILOGUE(62);
    }
    // tile 63: units 126,127 (full drain only at the very end)
    {
        ACC_INIT();
        WAITV(4);  COMPUTE_HALF(126);
        WAITV(0);  COMPUTE_HALF(127);
        __builtin_amdgcn_sched_barrier(0);
        EPILOGUE(63);
    }

#undef STAGE
#undef COMPUTE_HALF
#undef ACC_INIT
#undef WAITV
#undef EPILOGUE

    __syncthreads();   // waves are desynced; resync before LDS reuse

    // block-end reduction: quad-lane shuffle, then combine the 4 wn waves in LDS
#pragma unroll
    for (int mt = 0; mt < 4; mt++)
#pragma unroll
        for (int reg = 0; reg < 4; reg++) {
            float vsum = rsum[mt][reg];
            vsum += __shfl_xor(vsum, 1, 64);
            vsum += __shfl_xor(vsum, 2, 64);
            vsum += __shfl_xor(vsum, 4, 64);
            vsum += __shfl_xor(vsum, 8, 64);
            if (tcol == 0) {
                int lrow = wm * 64 + mt * 16 + quad * 4 + reg;
                ((float*)lds)[wn * 128 + lrow] = vsum;
            }
        }
    __syncthreads();
    if (tid < BM) {
        const float* lf = (const float*)lds;
        float t = lf[tid] + lf[128 + tid] + lf[256 + tid] + lf[384 + tid];
        partial[(size_t)s * NB + rb + tid] = t;
    }
}

// ---------------------------------------------------------------------------
// Kernel 3: loss = mean_i( log(sum_strips partial[s][i]) - pos_i )
// Widened: 32 blocks x 256 thr (1 row/thread, coalesced), device atomicAdd
// of per-block contributions into out[0] (zeroed by prep).
// ---------------------------------------------------------------------------
__global__ __launch_bounds__(256) void finalize_kernel(
    const float* __restrict__ partial, const float* __restrict__ pos,
    float* __restrict__ out)
{
    const int i = blockIdx.x * 256 + threadIdx.x;   // 0..8191
    float tot = partial[i] + partial[NB + i] + partial[2 * NB + i]
              + partial[3 * NB + i];
    float sv = logf(tot) - pos[i];
#pragma unroll
    for (int off = 32; off > 0; off >>= 1) sv += __shfl_down(sv, off, 64);
    __shared__ float wsum[4];
    const int t = threadIdx.x;
    if ((t & 63) == 0) wsum[t >> 6] = sv;
    __syncthreads();
    if (t == 0) {
        float blk = (wsum[0] + wsum[1]) + (wsum[2] + wsum[3]);
        atomicAdd(out, blk / (float)NB);
    }
}

extern "C" void kernel_launch(void* const* d_in, const int* in_sizes, int n_in,
                              void* d_out, int out_size, void* d_ws, size_t ws_size,
                              hipStream_t stream) {
    const float* u = (const float*)d_in[0];
    const float* v = (const float*)d_in[1];
    float* out = (float*)d_out;

    char* ws = (char*)d_ws;
    __hip_bfloat16* W = (__hip_bfloat16*)ws;                      // 8 MB
    float* partial = (float*)(ws + (size_t)NW * ND * sizeof(__hip_bfloat16));
    float* pos     = partial + NSTRIP * NB;                       // 8192 floats

    prep_kernel<<<NW / 8, 512, 0, stream>>>(u, v, W, out);
    dcl_main<<<256, 512, 0, stream>>>(W, partial, pos);
    finalize_kernel<<<NB / 256, 256, 0, stream>>>(partial, pos, out);
}